// Round 1
// baseline (10848.451 us; speedup 1.0000x reference)
//
#include <hip/hip_runtime.h>

#define NN 20000
#define NE 400000
#define CC 128
#define HH 8
#define DD 16
#define BBg 32
#define NC (NN * CC)      // 2,560,000
#define NHt (NN * HH)     // 160,000

// ---------------------------------------------------------------------------
// GEMM: Y[M,128] = X[M,128] @ W[128,128] + b   (fp32, W fully in LDS)
// block = 256 threads, 32 rows per block, thread tile = 2 rows x 8 cols
// grid.y selects which of 2 projections (different X, W, b, Y)
// ---------------------------------------------------------------------------
__global__ __launch_bounds__(256) void proj_gemm(
    const float* __restrict__ X0, const float* __restrict__ X1,
    const float* __restrict__ Wb, const float* __restrict__ Bb,
    float* __restrict__ Y0, float* __restrict__ Y1)
{
    const int t = blockIdx.y;
    const float* X = t ? X1 : X0;
    const float* W = Wb + (size_t)t * CC * CC;
    const float* bias = Bb + t * CC;
    float* Y = t ? Y1 : Y0;

    __shared__ float Ws[CC * CC];   // 64 KB
    __shared__ float Xs[32 * CC];   // 16 KB
    const int tid = threadIdx.x;
    for (int i = tid * 4; i < CC * CC; i += 1024)
        *(float4*)&Ws[i] = *(const float4*)&W[i];
    const int row0 = blockIdx.x * 32;
    for (int i = tid * 4; i < 32 * CC; i += 1024) {
        int r = i >> 7, c = i & 127;
        *(float4*)&Xs[i] = *(const float4*)&X[(size_t)(row0 + r) * CC + c];
    }
    __syncthreads();

    const int rg = (tid >> 4) * 2;      // row pair within tile
    const int c0 = (tid & 15) * 8;      // col group
    float acc0[8] = {}, acc1[8] = {};
    for (int k = 0; k < CC; k += 4) {
        float4 xa4 = *(const float4*)&Xs[rg * CC + k];
        float4 xb4 = *(const float4*)&Xs[(rg + 1) * CC + k];
        float xa[4] = {xa4.x, xa4.y, xa4.z, xa4.w};
        float xb[4] = {xb4.x, xb4.y, xb4.z, xb4.w};
#pragma unroll
        for (int kk = 0; kk < 4; kk++) {
            const float* wrow = &Ws[(k + kk) * CC + c0];
            float4 w0 = *(const float4*)&wrow[0];
            float4 w1 = *(const float4*)&wrow[4];
            float wv[8] = {w0.x, w0.y, w0.z, w0.w, w1.x, w1.y, w1.z, w1.w};
#pragma unroll
            for (int j = 0; j < 8; j++) {
                acc0[j] = fmaf(xa[kk], wv[j], acc0[j]);
                acc1[j] = fmaf(xb[kk], wv[j], acc1[j]);
            }
        }
    }
    const int row = row0 + rg;
    alignas(16) float outa[8], outb[8];
#pragma unroll
    for (int j = 0; j < 8; j++) {
        float bv = bias[c0 + j];
        outa[j] = acc0[j] + bv;
        outb[j] = acc1[j] + bv;
    }
    *(float4*)&Y[(size_t)row * CC + c0]           = *(float4*)&outa[0];
    *(float4*)&Y[(size_t)row * CC + c0 + 4]       = *(float4*)&outa[4];
    *(float4*)&Y[(size_t)(row + 1) * CC + c0]     = *(float4*)&outb[0];
    *(float4*)&Y[(size_t)(row + 1) * CC + c0 + 4] = *(float4*)&outb[4];
}

// ---------------------------------------------------------------------------
// Semantic-attention column sums: colsum[s][c] += sum_n tanh((relu(O_s)@Kw+Kb)[n][c])
// Same GEMM structure; epilogue reduces over rows instead of storing Y.
// grid.y = stack index s in 0..3; input = Obase + s*NC
// ---------------------------------------------------------------------------
__global__ __launch_bounds__(256) void semcol_gemm(
    const float* __restrict__ Obase, const float* __restrict__ Kw,
    const float* __restrict__ Kb, float* __restrict__ colsum)
{
    const int s = blockIdx.y;
    const float* X = Obase + (size_t)s * NC;

    __shared__ float Ws[CC * CC];
    __shared__ float Xs[32 * CC];
    const int tid = threadIdx.x;
    for (int i = tid * 4; i < CC * CC; i += 1024)
        *(float4*)&Ws[i] = *(const float4*)&Kw[i];
    const int row0 = blockIdx.x * 32;
    for (int i = tid * 4; i < 32 * CC; i += 1024) {
        int r = i >> 7, c = i & 127;
        float4 v = *(const float4*)&X[(size_t)(row0 + r) * CC + c];
        v.x = fmaxf(v.x, 0.f); v.y = fmaxf(v.y, 0.f);
        v.z = fmaxf(v.z, 0.f); v.w = fmaxf(v.w, 0.f);   // relu(o) is the stack entry
        *(float4*)&Xs[i] = v;
    }
    __syncthreads();

    const int rg = (tid >> 4) * 2;
    const int c0 = (tid & 15) * 8;
    float acc0[8] = {}, acc1[8] = {};
    for (int k = 0; k < CC; k += 4) {
        float4 xa4 = *(const float4*)&Xs[rg * CC + k];
        float4 xb4 = *(const float4*)&Xs[(rg + 1) * CC + k];
        float xa[4] = {xa4.x, xa4.y, xa4.z, xa4.w};
        float xb[4] = {xb4.x, xb4.y, xb4.z, xb4.w};
#pragma unroll
        for (int kk = 0; kk < 4; kk++) {
            const float* wrow = &Ws[(k + kk) * CC + c0];
            float4 w0 = *(const float4*)&wrow[0];
            float4 w1 = *(const float4*)&wrow[4];
            float wv[8] = {w0.x, w0.y, w0.z, w0.w, w1.x, w1.y, w1.z, w1.w};
#pragma unroll
            for (int j = 0; j < 8; j++) {
                acc0[j] = fmaf(xa[kk], wv[j], acc0[j]);
                acc1[j] = fmaf(xb[kk], wv[j], acc1[j]);
            }
        }
    }
    float part[8];
#pragma unroll
    for (int j = 0; j < 8; j++) {
        float bv = Kb[c0 + j];
        part[j] = tanhf(acc0[j] + bv) + tanhf(acc1[j] + bv);
    }
    __syncthreads();                 // done with Xs as X; reuse as reduction scratch
    float* red = Xs;                 // [16][128]
#pragma unroll
    for (int j = 0; j < 8; j++) red[(tid >> 4) * CC + c0 + j] = part[j];
    __syncthreads();
    if (tid < CC) {
        float sum = 0.f;
#pragma unroll
        for (int r = 0; r < 16; r++) sum += red[r * CC + tid];
        unsafeAtomicAdd(&colsum[s * CC + tid], sum);
    }
}

// ---------------------------------------------------------------------------
// Per-node attention logits for one edge type: al_s/al_d [N,H]; also zeroes z.
// ---------------------------------------------------------------------------
__global__ __launch_bounds__(256) void al_kernel(
    const float* __restrict__ hsrc, const float* __restrict__ hdst,
    const float* __restrict__ avs, const float* __restrict__ avd,
    float* __restrict__ als, float* __restrict__ ald, float* __restrict__ z)
{
    const int idx = blockIdx.x * 256 + threadIdx.x;
    if (idx >= NHt) return;
    const int n = idx >> 3, h = idx & 7;
    const float* ps = hsrc + (size_t)n * CC + h * DD;
    const float* pd = hdst + (size_t)n * CC + h * DD;
    float s1 = 0.f, s2 = 0.f;
#pragma unroll
    for (int d = 0; d < DD; d += 4) {
        float4 hv = *(const float4*)&ps[d];
        float4 av = *(const float4*)&avs[h * DD + d];
        s1 += hv.x * av.x + hv.y * av.y + hv.z * av.z + hv.w * av.w;
        float4 hw = *(const float4*)&pd[d];
        float4 aw = *(const float4*)&avd[h * DD + d];
        s2 += hw.x * aw.x + hw.y * aw.y + hw.z * aw.z + hw.w * aw.w;
    }
    als[idx] = s1;
    ald[idx] = s2;
    z[idx] = 0.f;   // zero-init softmax denominator (covers every [n,h] exactly once)
}

// ---------------------------------------------------------------------------
// Edge pass 1: ex = exp(leaky_relu(al_s[src]+al_d[dst])), z[dst] += ex.
// (no max-subtraction: |sc| << 1 with 0.05-scale activations, mathematically identical)
// ---------------------------------------------------------------------------
__global__ __launch_bounds__(256) void edge_pass1(
    const int* __restrict__ ei, const float* __restrict__ als,
    const float* __restrict__ ald, float* __restrict__ ex, float* __restrict__ z)
{
    const int e = blockIdx.x * 256 + threadIdx.x;
    if (e >= NE) return;
    const int src = ei[e], dst = ei[NE + e];
    float4 sa = *(const float4*)&als[src * 8];
    float4 sb = *(const float4*)&als[src * 8 + 4];
    float4 da = *(const float4*)&ald[dst * 8];
    float4 db = *(const float4*)&ald[dst * 8 + 4];
    float v[8] = {sa.x + da.x, sa.y + da.y, sa.z + da.z, sa.w + da.w,
                  sb.x + db.x, sb.y + db.y, sb.z + db.z, sb.w + db.w};
    alignas(16) float exv[8];
#pragma unroll
    for (int h = 0; h < 8; h++) {
        float t = v[h];
        t = t > 0.f ? t : 0.2f * t;
        float e_ = __expf(t);
        exv[h] = e_;
        unsafeAtomicAdd(&z[dst * 8 + h], e_);
    }
    *(float4*)&ex[e * 8]     = *(float4*)&exv[0];
    *(float4*)&ex[e * 8 + 4] = *(float4*)&exv[4];
}

// ---------------------------------------------------------------------------
// Edge pass 2: o[dst] += (ex/z[dst]) * hsrc[src].  32 lanes per edge, float4 per lane.
// ---------------------------------------------------------------------------
__global__ __launch_bounds__(256) void edge_pass2(
    const int* __restrict__ ei, const float* __restrict__ ex,
    const float* __restrict__ z, const float* __restrict__ hsrc,
    float* __restrict__ o)
{
    const long long gid = (long long)blockIdx.x * 256 + threadIdx.x;
    const int e = (int)(gid >> 5);
    if (e >= NE) return;
    const int lane = (int)(gid & 31);
    const int c0 = lane * 4;
    const int h = lane >> 2;
    const int src = ei[e], dst = ei[NE + e];
    const float alpha = ex[e * 8 + h] / z[dst * 8 + h];
    float4 xv = *(const float4*)&hsrc[(size_t)src * CC + c0];
    float* op = &o[(size_t)dst * CC + c0];
    unsafeAtomicAdd(op + 0, alpha * xv.x);
    unsafeAtomicAdd(op + 1, alpha * xv.y);
    unsafeAtomicAdd(op + 2, alpha * xv.z);
    unsafeAtomicAdd(op + 3, alpha * xv.w);
}

// ---------------------------------------------------------------------------
// Semantic softmax weights: score[s] = dot(q, colsum[s]) / N; softmax per target type.
// ---------------------------------------------------------------------------
__global__ __launch_bounds__(128) void attn_kernel(
    const float* __restrict__ colsum, const float* __restrict__ q,
    float* __restrict__ attn)
{
    const int tid = threadIdx.x;  // 128
    const float qc = q[tid];
    __shared__ float part[2][4];
    float p[4];
#pragma unroll
    for (int s = 0; s < 4; s++) {
        float v = qc * colsum[s * CC + tid];
        for (int off = 32; off > 0; off >>= 1) v += __shfl_down(v, off);
        p[s] = v;
    }
    if ((tid & 63) == 0) {
        int w = tid >> 6;
#pragma unroll
        for (int s = 0; s < 4; s++) part[w][s] = p[s];
    }
    __syncthreads();
    if (tid == 0) {
        float sc[4];
#pragma unroll
        for (int s = 0; s < 4; s++) sc[s] = (part[0][s] + part[1][s]) / (float)NN;
#pragma unroll
        for (int t = 0; t < 2; t++) {
            float m = fmaxf(sc[2 * t], sc[2 * t + 1]);
            float e0 = expf(sc[2 * t] - m), e1 = expf(sc[2 * t + 1] - m);
            float inv = 1.f / (e0 + e1);
            attn[2 * t] = e0 * inv;
            attn[2 * t + 1] = e1 * inv;
        }
    }
}

// ---------------------------------------------------------------------------
// x_t = attn[t,0]*relu(o_t0) + attn[t,1]*relu(o_t1)   (result >=0, so outer relu is id)
// ---------------------------------------------------------------------------
__global__ __launch_bounds__(256) void combine_kernel(
    const float* __restrict__ o, const float* __restrict__ attn,
    float* __restrict__ x0, float* __restrict__ x1)
{
    const int i = blockIdx.x * 256 + threadIdx.x;
    if (i >= NC) return;
    const float a0 = attn[0], a1 = attn[1], a2 = attn[2], a3 = attn[3];
    x0[i] = a0 * fmaxf(o[i], 0.f) + a1 * fmaxf(o[(size_t)NC + i], 0.f);
    x1[i] = a2 * fmaxf(o[2 * (size_t)NC + i], 0.f) + a3 * fmaxf(o[3 * (size_t)NC + i], 0.f);
}

// ---------------------------------------------------------------------------
// Pooling: per-graph max & sum (values >= 0 so uint-bit atomicMax is order-correct
// and 0-init matches the reference's -inf->0 replacement). batch is sorted, so each
// thread run-length-compresses 8 consecutive nodes before hitting atomics.
// ---------------------------------------------------------------------------
__global__ __launch_bounds__(256) void pool_kernel(
    const float* __restrict__ x0, const float* __restrict__ x1,
    const int* __restrict__ b0, const int* __restrict__ b1,
    float* __restrict__ fmaxb, float* __restrict__ fsumb)
{
    const int t = blockIdx.y;
    const float* x = t ? x1 : x0;
    const int* batch = t ? b1 : b0;
    const int i = blockIdx.x * 256 + threadIdx.x;   // (N/8)*C total
    if (i >= (NN / 8) * CC) return;
    const int g = i >> 7, c = i & 127;
    const int n0 = g * 8;
    int curb = batch[n0];
    float vmax = 0.f, vsum = 0.f;
    for (int k = 0; k < 8; k++) {
        int n = n0 + k;
        int b = batch[n];
        float v = x[(size_t)n * CC + c];
        if (b != curb) {
            atomicMax((unsigned*)&fmaxb[(t * BBg + curb) * CC + c], __float_as_uint(vmax));
            unsafeAtomicAdd(&fsumb[(t * BBg + curb) * CC + c], vsum);
            curb = b; vmax = 0.f; vsum = 0.f;
        }
        vmax = fmaxf(vmax, v);
        vsum += v;
    }
    atomicMax((unsigned*)&fmaxb[(t * BBg + curb) * CC + c], __float_as_uint(vmax));
    unsafeAtomicAdd(&fsumb[(t * BBg + curb) * CC + c], vsum);
}

// graph sizes via binary search on the sorted batch arrays (pure writes, no init needed)
__global__ void cnt_kernel(const int* __restrict__ b0, const int* __restrict__ b1,
                           float* __restrict__ cnt)
{
    const int tid = threadIdx.x;
    if (tid >= 2 * BBg) return;
    const int* batch = (tid >= BBg) ? b1 : b0;
    const int b = tid & (BBg - 1);
    int lo0 = 0, hi0 = NN;
    while (lo0 < hi0) { int mid = (lo0 + hi0) >> 1; if (batch[mid] < b) lo0 = mid + 1; else hi0 = mid; }
    int lo1 = lo0, hi1 = NN;
    while (lo1 < hi1) { int mid = (lo1 + hi1) >> 1; if (batch[mid] < b + 1) lo1 = mid + 1; else hi1 = mid; }
    cnt[tid] = (float)(lo1 - lo0);
}

// ---------------------------------------------------------------------------
// Head: assemble feat [32,512], PairNorm(PN-SI, scale=100), 3-layer MLP -> out[32,2]
// single block, 512 threads. LDS: 64+16+8 KB.
// ---------------------------------------------------------------------------
__global__ __launch_bounds__(512) void head_kernel(
    const float* __restrict__ fmaxb, const float* __restrict__ fsumb,
    const float* __restrict__ cnt,
    const float* __restrict__ W1, const float* __restrict__ bb1,
    const float* __restrict__ W2, const float* __restrict__ bb2,
    const float* __restrict__ W3, const float* __restrict__ bb3,
    float* __restrict__ out)
{
    __shared__ float F[32][512];
    __shared__ float scale[32];
    __shared__ float H1s[32][128];
    __shared__ float H2s[32][64];
    const int tid = threadIdx.x;
    const int j = tid;                      // feat column 0..511
    const int tt = j >> 8;                  // 0: bold pool, 1: dti pool
    const int jj = j & 255;
    const bool ismax = jj < 128;
    const int c = jj & 127;
    float csum = 0.f;
    for (int b = 0; b < 32; b++) {
        float v;
        if (ismax) v = fmaxb[(tt * BBg + b) * CC + c];
        else       v = fsumb[(tt * BBg + b) * CC + c] / fmaxf(cnt[tt * BBg + b], 1.f);
        F[b][j] = v;
        csum += v;
    }
    const float cmean = csum * (1.f / 32.f);
    for (int b = 0; b < 32; b++) F[b][j] -= cmean;
    __syncthreads();
    {   // row norms
        const int b = tid >> 4, l = tid & 15;
        float s = 0.f;
        for (int jx = l; jx < 512; jx += 16) { float v = F[b][jx]; s += v * v; }
        for (int off = 8; off > 0; off >>= 1) s += __shfl_down(s, off);
        if (l == 0) scale[b] = 100.f / sqrtf(1e-6f + s);
    }
    __syncthreads();
    for (int b = 0; b < 32; b++) F[b][j] *= scale[b];
    __syncthreads();
    {   // lin1: [32,512]@[512,128] -> relu
        const int co = tid & 127, bg = tid >> 7;   // 4 row groups of 8
        float acc[8] = {};
        for (int k = 0; k < 512; k++) {
            float w = W1[k * 128 + co];
#pragma unroll
            for (int r = 0; r < 8; r++) acc[r] = fmaf(F[bg * 8 + r][k], w, acc[r]);
        }
        float bv = bb1[co];
#pragma unroll
        for (int r = 0; r < 8; r++) H1s[bg * 8 + r][co] = fmaxf(acc[r] + bv, 0.f);
    }
    __syncthreads();
    {   // lin2: [32,128]@[128,64] -> relu
        const int co = tid & 63, bg = tid >> 6;    // 8 row groups of 4
        float acc[4] = {};
        for (int k = 0; k < 128; k++) {
            float w = W2[k * 64 + co];
#pragma unroll
            for (int r = 0; r < 4; r++) acc[r] = fmaf(H1s[bg * 4 + r][k], w, acc[r]);
        }
        float bv = bb2[co];
#pragma unroll
        for (int r = 0; r < 4; r++) H2s[bg * 4 + r][co] = fmaxf(acc[r] + bv, 0.f);
    }
    __syncthreads();
    if (tid < 64) {   // lin3: [32,64]@[64,2]
        const int b = tid >> 1, oc = tid & 1;
        float acc = bb3[oc];
        for (int k = 0; k < 64; k++) acc = fmaf(H2s[b][k], W3[k * 2 + oc], acc);
        out[b * 2 + oc] = acc;
    }
}

// ---------------------------------------------------------------------------
extern "C" void kernel_launch(void* const* d_in, const int* in_sizes, int n_in,
                              void* d_out, int out_size, void* d_ws, size_t ws_size,
                              hipStream_t stream)
{
    const float* x_bold = (const float*)d_in[0];
    const float* x_dti  = (const float*)d_in[1];
    const float* proj_w = (const float*)d_in[2];
    const float* proj_b = (const float*)d_in[3];
    const float* a_src  = (const float*)d_in[4];
    const float* a_dst  = (const float*)d_in[5];
    const float* k_w    = (const float*)d_in[6];
    const float* k_b    = (const float*)d_in[7];
    const float* qv     = (const float*)d_in[8];
    const float* lin1_w = (const float*)d_in[9];
    const float* lin1_b = (const float*)d_in[10];
    const float* lin2_w = (const float*)d_in[11];
    const float* lin2_b = (const float*)d_in[12];
    const float* lin3_w = (const float*)d_in[13];
    const float* lin3_b = (const float*)d_in[14];
    const int* eis[4] = {(const int*)d_in[15], (const int*)d_in[16],
                         (const int*)d_in[17], (const int*)d_in[18]};
    const int* batch_bold = (const int*)d_in[19];
    const int* batch_dti  = (const int*)d_in[20];

    float* ws = (float*)d_ws;
    float* h0   = ws;                      // [N,C]
    float* h1   = h0 + NC;                 // [N,C]
    float* obuf = h1 + NC;                 // 4x[N,C]: {t0s0(bb), t0s1(db), t1s0(bd), t1s1(dd)}
    float* x0   = obuf + 4 * (size_t)NC;   // [N,C]
    float* x1   = x0 + NC;                 // [N,C]
    float* als  = x1 + NC;                 // [N,H]
    float* ald  = als + NHt;               // [N,H]
    float* zb   = ald + NHt;               // [N,H]
    float* exb  = zb + NHt;                // [E,H]
    float* colsum = exb + (size_t)NE * HH; // [4,C]
    float* attn   = colsum + 4 * CC;       // [4]
    float* fmaxb  = attn + 4;              // [2,B,C]
    float* fsumb  = fmaxb + 2 * BBg * CC;  // [2,B,C]
    float* cnt    = fsumb + 2 * BBg * CC;  // [2,B]

    hipMemcpyAsync(x0, x_bold, (size_t)NC * sizeof(float), hipMemcpyDeviceToDevice, stream);
    hipMemcpyAsync(x1, x_dti,  (size_t)NC * sizeof(float), hipMemcpyDeviceToDevice, stream);

    // edge-type metadata: (src type, dst type, o-slot = t*2+s)
    const int est[4] = {0, 0, 1, 1};
    const int edt[4] = {0, 1, 0, 1};
    const int eoi[4] = {0, 2, 1, 3};

    for (int l = 0; l < 3; l++) {
        proj_gemm<<<dim3(625, 2), 256, 0, stream>>>(
            x0, x1, proj_w + (size_t)l * 2 * CC * CC, proj_b + l * 2 * CC, h0, h1);
        hipMemsetAsync(obuf, 0, 4 * (size_t)NC * sizeof(float), stream);
        hipMemsetAsync(colsum, 0, 4 * CC * sizeof(float), stream);
        for (int e = 0; e < 4; e++) {
            const float* hs = est[e] ? h1 : h0;
            const float* hd = edt[e] ? h1 : h0;
            al_kernel<<<625, 256, 0, stream>>>(
                hs, hd, a_src + (size_t)(l * 4 + e) * HH * DD,
                a_dst + (size_t)(l * 4 + e) * HH * DD, als, ald, zb);
            edge_pass1<<<(NE + 255) / 256, 256, 0, stream>>>(eis[e], als, ald, exb, zb);
            edge_pass2<<<NE * 32 / 256, 256, 0, stream>>>(
                eis[e], exb, zb, hs, obuf + (size_t)eoi[e] * NC);
        }
        semcol_gemm<<<dim3(625, 4), 256, 0, stream>>>(
            obuf, k_w + (size_t)l * CC * CC, k_b + l * CC, colsum);
        attn_kernel<<<1, 128, 0, stream>>>(colsum, qv + l * CC, attn);
        combine_kernel<<<(NC + 255) / 256, 256, 0, stream>>>(obuf, attn, x0, x1);
    }

    hipMemsetAsync(fmaxb, 0, 2 * 2 * BBg * CC * sizeof(float), stream);  // fmaxb+fsumb
    pool_kernel<<<dim3((NN / 8) * CC / 256, 2), 256, 0, stream>>>(
        x0, x1, batch_bold, batch_dti, fmaxb, fsumb);
    cnt_kernel<<<1, 64, 0, stream>>>(batch_bold, batch_dti, cnt);
    head_kernel<<<1, 512, 0, stream>>>(fmaxb, fsumb, cnt, lin1_w, lin1_b,
                                       lin2_w, lin2_b, lin3_w, lin3_b, (float*)d_out);
}

// Round 2
// 1746.740 us; speedup vs baseline: 6.2107x; 6.2107x over previous
//
#include <hip/hip_runtime.h>

#define NN 20000
#define NE 400000
#define CC 128
#define HH 8
#define DD 16
#define BBg 32
#define NC (NN * CC)      // 2,560,000
#define NHt (NN * HH)     // 160,000

// ===========================================================================
// CSR build (once per call, per edge type): dst-sorted src lists, no fp atomics
// ===========================================================================
__global__ __launch_bounds__(256) void hist_kernel(const int* __restrict__ ei,
                                                   int* __restrict__ deg)
{
    const int e = blockIdx.x * 256 + threadIdx.x;
    if (e >= NE) return;
    atomicAdd(&deg[ei[NE + e]], 1);
}

__global__ __launch_bounds__(1024) void scan_kernel(const int* __restrict__ deg,
                                                    int* __restrict__ rowptr,
                                                    int* __restrict__ cursor)
{
    __shared__ int part[1024];
    const int tid = threadIdx.x;
    const int base = tid * 20;                    // 1024*20 = 20480 >= NN
    int s = 0;
    for (int k = 0; k < 20; k++) { int i = base + k; if (i < NN) s += deg[i]; }
    part[tid] = s;
    __syncthreads();
    if (tid == 0) {
        int run = 0;
        for (int i = 0; i < 1024; i++) { int t = part[i]; part[i] = run; run += t; }
        rowptr[NN] = run;                         // == NE
    }
    __syncthreads();
    int run = part[tid];
    for (int k = 0; k < 20; k++) {
        int i = base + k;
        if (i < NN) { rowptr[i] = run; cursor[i] = run; run += deg[i]; }
    }
}

__global__ __launch_bounds__(256) void scatter_kernel(const int* __restrict__ ei,
                                                      int* __restrict__ cursor,
                                                      int* __restrict__ srcs)
{
    const int e = blockIdx.x * 256 + threadIdx.x;
    if (e >= NE) return;
    const int pos = atomicAdd(&cursor[ei[NE + e]], 1);
    srcs[pos] = ei[e];
}

// ===========================================================================
// GEMM: Y[M,128] = X[M,128] @ W[128,128] + b   (fp32, W fully in LDS)
// ===========================================================================
__global__ __launch_bounds__(256) void proj_gemm(
    const float* __restrict__ X0, const float* __restrict__ X1,
    const float* __restrict__ Wb, const float* __restrict__ Bb,
    float* __restrict__ Y0, float* __restrict__ Y1)
{
    const int t = blockIdx.y;
    const float* X = t ? X1 : X0;
    const float* W = Wb + (size_t)t * CC * CC;
    const float* bias = Bb + t * CC;
    float* Y = t ? Y1 : Y0;

    __shared__ float Ws[CC * CC];   // 64 KB
    __shared__ float Xs[32 * CC];   // 16 KB
    const int tid = threadIdx.x;
    for (int i = tid * 4; i < CC * CC; i += 1024)
        *(float4*)&Ws[i] = *(const float4*)&W[i];
    const int row0 = blockIdx.x * 32;
    for (int i = tid * 4; i < 32 * CC; i += 1024) {
        int r = i >> 7, c = i & 127;
        *(float4*)&Xs[i] = *(const float4*)&X[(size_t)(row0 + r) * CC + c];
    }
    __syncthreads();

    const int rg = (tid >> 4) * 2;
    const int c0 = (tid & 15) * 8;
    float acc0[8] = {}, acc1[8] = {};
    for (int k = 0; k < CC; k += 4) {
        float4 xa4 = *(const float4*)&Xs[rg * CC + k];
        float4 xb4 = *(const float4*)&Xs[(rg + 1) * CC + k];
        float xa[4] = {xa4.x, xa4.y, xa4.z, xa4.w};
        float xb[4] = {xb4.x, xb4.y, xb4.z, xb4.w};
#pragma unroll
        for (int kk = 0; kk < 4; kk++) {
            const float* wrow = &Ws[(k + kk) * CC + c0];
            float4 w0 = *(const float4*)&wrow[0];
            float4 w1 = *(const float4*)&wrow[4];
            float wv[8] = {w0.x, w0.y, w0.z, w0.w, w1.x, w1.y, w1.z, w1.w};
#pragma unroll
            for (int j = 0; j < 8; j++) {
                acc0[j] = fmaf(xa[kk], wv[j], acc0[j]);
                acc1[j] = fmaf(xb[kk], wv[j], acc1[j]);
            }
        }
    }
    const int row = row0 + rg;
    alignas(16) float outa[8], outb[8];
#pragma unroll
    for (int j = 0; j < 8; j++) {
        float bv = bias[c0 + j];
        outa[j] = acc0[j] + bv;
        outb[j] = acc1[j] + bv;
    }
    *(float4*)&Y[(size_t)row * CC + c0]           = *(float4*)&outa[0];
    *(float4*)&Y[(size_t)row * CC + c0 + 4]       = *(float4*)&outa[4];
    *(float4*)&Y[(size_t)(row + 1) * CC + c0]     = *(float4*)&outb[0];
    *(float4*)&Y[(size_t)(row + 1) * CC + c0 + 4] = *(float4*)&outb[4];
}

// ===========================================================================
// Semantic-attention column sums (input already relu'd by e2; fmaxf idempotent)
// ===========================================================================
__global__ __launch_bounds__(256) void semcol_gemm(
    const float* __restrict__ Obase, const float* __restrict__ Kw,
    const float* __restrict__ Kb, float* __restrict__ colsum)
{
    const int s = blockIdx.y;
    const float* X = Obase + (size_t)s * NC;

    __shared__ float Ws[CC * CC];
    __shared__ float Xs[32 * CC];
    const int tid = threadIdx.x;
    for (int i = tid * 4; i < CC * CC; i += 1024)
        *(float4*)&Ws[i] = *(const float4*)&Kw[i];
    const int row0 = blockIdx.x * 32;
    for (int i = tid * 4; i < 32 * CC; i += 1024) {
        int r = i >> 7, c = i & 127;
        float4 v = *(const float4*)&X[(size_t)(row0 + r) * CC + c];
        *(float4*)&Xs[i] = v;
    }
    __syncthreads();

    const int rg = (tid >> 4) * 2;
    const int c0 = (tid & 15) * 8;
    float acc0[8] = {}, acc1[8] = {};
    for (int k = 0; k < CC; k += 4) {
        float4 xa4 = *(const float4*)&Xs[rg * CC + k];
        float4 xb4 = *(const float4*)&Xs[(rg + 1) * CC + k];
        float xa[4] = {xa4.x, xa4.y, xa4.z, xa4.w};
        float xb[4] = {xb4.x, xb4.y, xb4.z, xb4.w};
#pragma unroll
        for (int kk = 0; kk < 4; kk++) {
            const float* wrow = &Ws[(k + kk) * CC + c0];
            float4 w0 = *(const float4*)&wrow[0];
            float4 w1 = *(const float4*)&wrow[4];
            float wv[8] = {w0.x, w0.y, w0.z, w0.w, w1.x, w1.y, w1.z, w1.w};
#pragma unroll
            for (int j = 0; j < 8; j++) {
                acc0[j] = fmaf(xa[kk], wv[j], acc0[j]);
                acc1[j] = fmaf(xb[kk], wv[j], acc1[j]);
            }
        }
    }
    float part[8];
#pragma unroll
    for (int j = 0; j < 8; j++) {
        float bv = Kb[c0 + j];
        part[j] = tanhf(acc0[j] + bv) + tanhf(acc1[j] + bv);
    }
    __syncthreads();
    float* red = Xs;                 // [16][128] reduction scratch
#pragma unroll
    for (int j = 0; j < 8; j++) red[(tid >> 4) * CC + c0 + j] = part[j];
    __syncthreads();
    if (tid < CC) {
        float sum = 0.f;
#pragma unroll
        for (int r = 0; r < 16; r++) sum += red[r * CC + tid];
        unsafeAtomicAdd(&colsum[s * CC + tid], sum);
    }
}

// ===========================================================================
// Per-node attention logits: als/ald [N,H]
// ===========================================================================
__global__ __launch_bounds__(256) void al_kernel(
    const float* __restrict__ hsrc, const float* __restrict__ hdst,
    const float* __restrict__ avs, const float* __restrict__ avd,
    float* __restrict__ als, float* __restrict__ ald)
{
    const int idx = blockIdx.x * 256 + threadIdx.x;
    if (idx >= NHt) return;
    const int n = idx >> 3, h = idx & 7;
    const float* ps = hsrc + (size_t)n * CC + h * DD;
    const float* pd = hdst + (size_t)n * CC + h * DD;
    float s1 = 0.f, s2 = 0.f;
#pragma unroll
    for (int d = 0; d < DD; d += 4) {
        float4 hv = *(const float4*)&ps[d];
        float4 av = *(const float4*)&avs[h * DD + d];
        s1 += hv.x * av.x + hv.y * av.y + hv.z * av.z + hv.w * av.w;
        float4 hw = *(const float4*)&pd[d];
        float4 aw = *(const float4*)&avd[h * DD + d];
        s2 += hw.x * aw.x + hw.y * aw.y + hw.z * aw.z + hw.w * aw.w;
    }
    als[idx] = s1;
    ald[idx] = s2;
}

// ===========================================================================
// Edge pass 1 (CSR): per (dst,h) thread: ex[pos] = exp(lrelu(als[src]+ald[dst])),
// z[dst,h] = plain register sum. No atomics.
// ===========================================================================
__global__ __launch_bounds__(256) void e1_kernel(
    const int* __restrict__ rowptr, const int* __restrict__ srcs,
    const float* __restrict__ als, const float* __restrict__ ald,
    float* __restrict__ exb, float* __restrict__ z)
{
    const int idx = blockIdx.x * 256 + threadIdx.x;
    if (idx >= NHt) return;
    const int dst = idx >> 3, h = idx & 7;
    const float aldv = ald[idx];
    const int p1 = rowptr[dst + 1];
    float zs = 0.f;
    for (int p = rowptr[dst]; p < p1; p++) {
        float s = als[srcs[p] * 8 + h] + aldv;
        s = s > 0.f ? s : 0.2f * s;
        const float e = __expf(s);
        exb[p * 8 + h] = e;
        zs += e;
    }
    z[idx] = zs;
}

// ===========================================================================
// Edge pass 2 (CSR): wave per dst, lane owns 2 channels. Single write per row,
// relu applied at the write (consumers use fmaxf -> idempotent).
// ===========================================================================
__global__ __launch_bounds__(256) void e2_kernel(
    const int* __restrict__ rowptr, const int* __restrict__ srcs,
    const float* __restrict__ exb, const float* __restrict__ z,
    const float* __restrict__ hsrc, float* __restrict__ o)
{
    const int dst = blockIdx.x * 4 + (threadIdx.x >> 6);
    const int lane = threadIdx.x & 63;
    const int h = lane >> 3;                 // (lane*2)/16
    const float zv = z[dst * 8 + h];
    const float zinv = zv > 0.f ? 1.f / zv : 0.f;
    float accx = 0.f, accy = 0.f;
    const int p1 = rowptr[dst + 1];
    for (int p = rowptr[dst]; p < p1; p++) {
        const float alpha = exb[p * 8 + h] * zinv;
        const float2 xv = *(const float2*)&hsrc[(size_t)srcs[p] * CC + lane * 2];
        accx = fmaf(alpha, xv.x, accx);
        accy = fmaf(alpha, xv.y, accy);
    }
    float2 outv = {fmaxf(accx, 0.f), fmaxf(accy, 0.f)};
    *(float2*)&o[(size_t)dst * CC + lane * 2] = outv;
}

// ===========================================================================
// Semantic softmax weights
// ===========================================================================
__global__ __launch_bounds__(128) void attn_kernel(
    const float* __restrict__ colsum, const float* __restrict__ q,
    float* __restrict__ attn)
{
    const int tid = threadIdx.x;
    const float qc = q[tid];
    __shared__ float part[2][4];
    float p[4];
#pragma unroll
    for (int s = 0; s < 4; s++) {
        float v = qc * colsum[s * CC + tid];
        for (int off = 32; off > 0; off >>= 1) v += __shfl_down(v, off);
        p[s] = v;
    }
    if ((tid & 63) == 0) {
        int w = tid >> 6;
#pragma unroll
        for (int s = 0; s < 4; s++) part[w][s] = p[s];
    }
    __syncthreads();
    if (tid == 0) {
        float sc[4];
#pragma unroll
        for (int s = 0; s < 4; s++) sc[s] = (part[0][s] + part[1][s]) / (float)NN;
#pragma unroll
        for (int t = 0; t < 2; t++) {
            float m = fmaxf(sc[2 * t], sc[2 * t + 1]);
            float e0 = expf(sc[2 * t] - m), e1 = expf(sc[2 * t + 1] - m);
            float inv = 1.f / (e0 + e1);
            attn[2 * t] = e0 * inv;
            attn[2 * t + 1] = e1 * inv;
        }
    }
}

// ===========================================================================
// x_t = attn[t,0]*o_t0 + attn[t,1]*o_t1   (o already relu'd)
// ===========================================================================
__global__ __launch_bounds__(256) void combine_kernel(
    const float* __restrict__ o, const float* __restrict__ attn,
    float* __restrict__ x0, float* __restrict__ x1)
{
    const int i = blockIdx.x * 256 + threadIdx.x;
    if (i >= NC) return;
    const float a0 = attn[0], a1 = attn[1], a2 = attn[2], a3 = attn[3];
    x0[i] = a0 * o[i] + a1 * o[(size_t)NC + i];
    x1[i] = a2 * o[2 * (size_t)NC + i] + a3 * o[3 * (size_t)NC + i];
}

// ===========================================================================
// Pooling (values >= 0: uint atomicMax ordering + 0-init == reference -inf->0)
// ===========================================================================
__global__ __launch_bounds__(256) void pool_kernel(
    const float* __restrict__ x0, const float* __restrict__ x1,
    const int* __restrict__ b0, const int* __restrict__ b1,
    float* __restrict__ fmaxb, float* __restrict__ fsumb)
{
    const int t = blockIdx.y;
    const float* x = t ? x1 : x0;
    const int* batch = t ? b1 : b0;
    const int i = blockIdx.x * 256 + threadIdx.x;
    if (i >= (NN / 8) * CC) return;
    const int g = i >> 7, c = i & 127;
    const int n0 = g * 8;
    int curb = batch[n0];
    float vmax = 0.f, vsum = 0.f;
    for (int k = 0; k < 8; k++) {
        int n = n0 + k;
        int b = batch[n];
        float v = x[(size_t)n * CC + c];
        if (b != curb) {
            atomicMax((unsigned*)&fmaxb[(t * BBg + curb) * CC + c], __float_as_uint(vmax));
            unsafeAtomicAdd(&fsumb[(t * BBg + curb) * CC + c], vsum);
            curb = b; vmax = 0.f; vsum = 0.f;
        }
        vmax = fmaxf(vmax, v);
        vsum += v;
    }
    atomicMax((unsigned*)&fmaxb[(t * BBg + curb) * CC + c], __float_as_uint(vmax));
    unsafeAtomicAdd(&fsumb[(t * BBg + curb) * CC + c], vsum);
}

__global__ void cnt_kernel(const int* __restrict__ b0, const int* __restrict__ b1,
                           float* __restrict__ cnt)
{
    const int tid = threadIdx.x;
    if (tid >= 2 * BBg) return;
    const int* batch = (tid >= BBg) ? b1 : b0;
    const int b = tid & (BBg - 1);
    int lo0 = 0, hi0 = NN;
    while (lo0 < hi0) { int mid = (lo0 + hi0) >> 1; if (batch[mid] < b) lo0 = mid + 1; else hi0 = mid; }
    int lo1 = lo0, hi1 = NN;
    while (lo1 < hi1) { int mid = (lo1 + hi1) >> 1; if (batch[mid] < b + 1) lo1 = mid + 1; else hi1 = mid; }
    cnt[tid] = (float)(lo1 - lo0);
}

// ===========================================================================
// Head: feat assembly + PairNorm + MLP
// ===========================================================================
__global__ __launch_bounds__(512) void head_kernel(
    const float* __restrict__ fmaxb, const float* __restrict__ fsumb,
    const float* __restrict__ cnt,
    const float* __restrict__ W1, const float* __restrict__ bb1,
    const float* __restrict__ W2, const float* __restrict__ bb2,
    const float* __restrict__ W3, const float* __restrict__ bb3,
    float* __restrict__ out)
{
    __shared__ float F[32][512];
    __shared__ float scale[32];
    __shared__ float H1s[32][128];
    __shared__ float H2s[32][64];
    const int tid = threadIdx.x;
    const int j = tid;
    const int tt = j >> 8;
    const int jj = j & 255;
    const bool ismax = jj < 128;
    const int c = jj & 127;
    float csum = 0.f;
    for (int b = 0; b < 32; b++) {
        float v;
        if (ismax) v = fmaxb[(tt * BBg + b) * CC + c];
        else       v = fsumb[(tt * BBg + b) * CC + c] / fmaxf(cnt[tt * BBg + b], 1.f);
        F[b][j] = v;
        csum += v;
    }
    const float cmean = csum * (1.f / 32.f);
    for (int b = 0; b < 32; b++) F[b][j] -= cmean;
    __syncthreads();
    {
        const int b = tid >> 4, l = tid & 15;
        float s = 0.f;
        for (int jx = l; jx < 512; jx += 16) { float v = F[b][jx]; s += v * v; }
        for (int off = 8; off > 0; off >>= 1) s += __shfl_down(s, off);
        if (l == 0) scale[b] = 100.f / sqrtf(1e-6f + s);
    }
    __syncthreads();
    for (int b = 0; b < 32; b++) F[b][j] *= scale[b];
    __syncthreads();
    {
        const int co = tid & 127, bg = tid >> 7;
        float acc[8] = {};
        for (int k = 0; k < 512; k++) {
            float w = W1[k * 128 + co];
#pragma unroll
            for (int r = 0; r < 8; r++) acc[r] = fmaf(F[bg * 8 + r][k], w, acc[r]);
        }
        float bv = bb1[co];
#pragma unroll
        for (int r = 0; r < 8; r++) H1s[bg * 8 + r][co] = fmaxf(acc[r] + bv, 0.f);
    }
    __syncthreads();
    {
        const int co = tid & 63, bg = tid >> 6;
        float acc[4] = {};
        for (int k = 0; k < 128; k++) {
            float w = W2[k * 64 + co];
#pragma unroll
            for (int r = 0; r < 4; r++) acc[r] = fmaf(H1s[bg * 4 + r][k], w, acc[r]);
        }
        float bv = bb2[co];
#pragma unroll
        for (int r = 0; r < 4; r++) H2s[bg * 4 + r][co] = fmaxf(acc[r] + bv, 0.f);
    }
    __syncthreads();
    if (tid < 64) {
        const int b = tid >> 1, oc = tid & 1;
        float acc = bb3[oc];
        for (int k = 0; k < 64; k++) acc = fmaf(H2s[b][k], W3[k * 2 + oc], acc);
        out[b * 2 + oc] = acc;
    }
}

// ===========================================================================
extern "C" void kernel_launch(void* const* d_in, const int* in_sizes, int n_in,
                              void* d_out, int out_size, void* d_ws, size_t ws_size,
                              hipStream_t stream)
{
    const float* x_bold = (const float*)d_in[0];
    const float* x_dti  = (const float*)d_in[1];
    const float* proj_w = (const float*)d_in[2];
    const float* proj_b = (const float*)d_in[3];
    const float* a_src  = (const float*)d_in[4];
    const float* a_dst  = (const float*)d_in[5];
    const float* k_w    = (const float*)d_in[6];
    const float* k_b    = (const float*)d_in[7];
    const float* qv     = (const float*)d_in[8];
    const float* lin1_w = (const float*)d_in[9];
    const float* lin1_b = (const float*)d_in[10];
    const float* lin2_w = (const float*)d_in[11];
    const float* lin2_b = (const float*)d_in[12];
    const float* lin3_w = (const float*)d_in[13];
    const float* lin3_b = (const float*)d_in[14];
    const int* eis[4] = {(const int*)d_in[15], (const int*)d_in[16],
                         (const int*)d_in[17], (const int*)d_in[18]};
    const int* batch_bold = (const int*)d_in[19];
    const int* batch_dti  = (const int*)d_in[20];

    float* ws = (float*)d_ws;
    float* h0   = ws;                      // [N,C]
    float* h1   = h0 + NC;                 // [N,C]
    float* obuf = h1 + NC;                 // 4x[N,C]: slots {0:bb,1:db,2:bd,3:dd}
    float* x0   = obuf + 4 * (size_t)NC;   // [N,C]
    float* x1   = x0 + NC;                 // [N,C]
    float* als  = x1 + NC;                 // [N,H]
    float* ald  = als + NHt;               // [N,H]
    float* zb   = ald + NHt;               // [N,H]
    float* exb  = zb + NHt;                // [E,H] (CSR-position indexed)
    float* colsum = exb + (size_t)NE * HH; // [4,C]
    float* attn   = colsum + 4 * CC;       // [4]
    float* fmaxb  = attn + 4;              // [2,B,C]
    float* fsumb  = fmaxb + 2 * BBg * CC;  // [2,B,C]
    float* cnt    = fsumb + 2 * BBg * CC;  // [2,B]
    // int scratch after the float region
    int* iws    = (int*)(cnt + 2 * BBg);
    int* deg    = iws;                     // [N]
    int* cursor = deg + NN;                // [N]
    int* rowptr[4]; int* srcs[4];
    int* ip = cursor + NN;
    for (int e = 0; e < 4; e++) { rowptr[e] = ip; ip += NN + 1; srcs[e] = ip; ip += NE; }

    // ---- build CSR per edge type (edge lists constant across layers) ----
    for (int e = 0; e < 4; e++) {
        hipMemsetAsync(deg, 0, NN * sizeof(int), stream);
        hist_kernel<<<(NE + 255) / 256, 256, 0, stream>>>(eis[e], deg);
        scan_kernel<<<1, 1024, 0, stream>>>(deg, rowptr[e], cursor);
        scatter_kernel<<<(NE + 255) / 256, 256, 0, stream>>>(eis[e], cursor, srcs[e]);
    }

    hipMemcpyAsync(x0, x_bold, (size_t)NC * sizeof(float), hipMemcpyDeviceToDevice, stream);
    hipMemcpyAsync(x1, x_dti,  (size_t)NC * sizeof(float), hipMemcpyDeviceToDevice, stream);

    const int est[4] = {0, 0, 1, 1};
    const int eoi[4] = {0, 2, 1, 3};
    const int edt[4] = {0, 1, 0, 1};

    for (int l = 0; l < 3; l++) {
        proj_gemm<<<dim3(625, 2), 256, 0, stream>>>(
            x0, x1, proj_w + (size_t)l * 2 * CC * CC, proj_b + l * 2 * CC, h0, h1);
        hipMemsetAsync(colsum, 0, 4 * CC * sizeof(float), stream);
        for (int e = 0; e < 4; e++) {
            const float* hs = est[e] ? h1 : h0;
            const float* hd = edt[e] ? h1 : h0;
            al_kernel<<<625, 256, 0, stream>>>(
                hs, hd, a_src + (size_t)(l * 4 + e) * HH * DD,
                a_dst + (size_t)(l * 4 + e) * HH * DD, als, ald);
            e1_kernel<<<625, 256, 0, stream>>>(rowptr[e], srcs[e], als, ald, exb, zb);
            e2_kernel<<<NN / 4, 256, 0, stream>>>(rowptr[e], srcs[e], exb, zb, hs,
                                                  obuf + (size_t)eoi[e] * NC);
        }
        semcol_gemm<<<dim3(625, 4), 256, 0, stream>>>(
            obuf, k_w + (size_t)l * CC * CC, k_b + l * CC, colsum);
        attn_kernel<<<1, 128, 0, stream>>>(colsum, qv + l * CC, attn);
        combine_kernel<<<(NC + 255) / 256, 256, 0, stream>>>(obuf, attn, x0, x1);
    }

    hipMemsetAsync(fmaxb, 0, 2 * 2 * BBg * CC * sizeof(float), stream);
    pool_kernel<<<dim3((NN / 8) * CC / 256, 2), 256, 0, stream>>>(
        x0, x1, batch_bold, batch_dti, fmaxb, fsumb);
    cnt_kernel<<<1, 64, 0, stream>>>(batch_bold, batch_dti, cnt);
    head_kernel<<<1, 512, 0, stream>>>(fmaxb, fsumb, cnt, lin1_w, lin1_b,
                                       lin2_w, lin2_b, lin3_w, lin3_b, (float*)d_out);
}